// Round 1
// baseline (453.042 us; speedup 1.0000x reference)
//
#include <hip/hip_runtime.h>

// Problem constants (from reference setup_inputs)
#define BB 8
#define CC 3
#define HH 512
#define WW 1024
#define HW (HH * WW)            // 524288 = 2^19
#define NTOT (BB * HW)          // 4194304
#define SAME_RANGE 0.2f

// Compute flat target index for a source pixel tid in [0, NTOT)
__device__ __forceinline__ int target_idx(const float* __restrict__ flow, int tid,
                                          int& b, int& rem) {
    b = tid >> 19;              // / HW
    rem = tid & (HW - 1);       // % HW
    int y = rem >> 10;          // / WW
    int x = rem & (WW - 1);     // % WW
    float fx = flow[(b * 2 + 0) * HW + rem] + (float)x;
    float fy = flow[(b * 2 + 1) * HW + rem] + (float)y;
    fx = fminf(fmaxf(fx, 0.0f), (float)(WW - 1));
    fy = fminf(fmaxf(fy, 0.0f), (float)(HH - 1));
    int xi = (int)rintf(fx);    // round-half-to-even, matches jnp.round
    int yi = (int)rintf(fy);
    return b * HW + yi * WW + xi;
}

// Pass 1: per-target min depth via int atomicMin (depth >= 0 so bits are monotone)
__global__ void zmin_kernel(const float* __restrict__ flow,
                            const float* __restrict__ depth,
                            int* __restrict__ dlut) {
    int tid = blockIdx.x * blockDim.x + threadIdx.x;
    if (tid >= NTOT) return;
    int b, rem;
    int idx = target_idx(flow, tid, b, rem);
    float d = depth[tid];
    atomicMin(&dlut[idx], __float_as_int(d));
}

// Pass 2: splat obj channels into d_out (used as sum accumulator) + count into cnts
__global__ void splat_kernel(const float* __restrict__ obj,
                             const float* __restrict__ flow,
                             const float* __restrict__ depth,
                             const int* __restrict__ dlut,
                             float* __restrict__ sums,   // d_out, (B,C,H,W) layout
                             float* __restrict__ cnts) { // (B,H,W) flat
    int tid = blockIdx.x * blockDim.x + threadIdx.x;
    if (tid >= NTOT) return;
    int b, rem;
    int idx = target_idx(flow, tid, b, rem);
    float d = depth[tid];
    float dmin = __int_as_float(dlut[idx]);
    if (d <= dmin + SAME_RANGE) {
        int trem = idx & (HW - 1);   // target (y*W+x); target batch == b
        atomicAdd(&sums[(b * CC + 0) * HW + trem], obj[(b * CC + 0) * HW + rem]);
        atomicAdd(&sums[(b * CC + 1) * HW + trem], obj[(b * CC + 1) * HW + rem]);
        atomicAdd(&sums[(b * CC + 2) * HW + trem], obj[(b * CC + 2) * HW + rem]);
        atomicAdd(&cnts[idx], 1.0f);
    }
}

// Pass 3: out = cnt > 0 ? sum / cnt : 0  (sums already 0 where cnt==0)
__global__ void finalize_kernel(float* __restrict__ out,
                                const float* __restrict__ cnts) {
    int tid = blockIdx.x * blockDim.x + threadIdx.x;
    if (tid >= NTOT) return;
    int b = tid >> 19;
    int rem = tid & (HW - 1);
    float c = cnts[tid];
    if (c > 0.0f) {
        float inv_c = c; // keep exact division to match ref: sums / cnts
        out[(b * CC + 0) * HW + rem] = out[(b * CC + 0) * HW + rem] / inv_c;
        out[(b * CC + 1) * HW + rem] = out[(b * CC + 1) * HW + rem] / inv_c;
        out[(b * CC + 2) * HW + rem] = out[(b * CC + 2) * HW + rem] / inv_c;
    }
    // c == 0: sums are 0 from the memset, which is the reference's 0 output.
}

extern "C" void kernel_launch(void* const* d_in, const int* in_sizes, int n_in,
                              void* d_out, int out_size, void* d_ws, size_t ws_size,
                              hipStream_t stream) {
    const float* obj   = (const float*)d_in[0];
    const float* flow  = (const float*)d_in[1];
    const float* depth = (const float*)d_in[2];
    float* out = (float*)d_out;

    int*   dlut = (int*)d_ws;
    float* cnts = (float*)((char*)d_ws + (size_t)NTOT * sizeof(int));

    // Init: dlut to 0x7F7F7F7F (~3.4e38, > any depth), cnts and out to zero.
    hipMemsetAsync(dlut, 0x7F, (size_t)NTOT * sizeof(int), stream);
    hipMemsetAsync(cnts, 0,    (size_t)NTOT * sizeof(float), stream);
    hipMemsetAsync(out,  0,    (size_t)NTOT * CC * sizeof(float), stream);

    dim3 block(256);
    dim3 grid(NTOT / 256);   // NTOT divisible by 256
    zmin_kernel<<<grid, block, 0, stream>>>(flow, depth, dlut);
    splat_kernel<<<grid, block, 0, stream>>>(obj, flow, depth, dlut, out, cnts);
    finalize_kernel<<<grid, block, 0, stream>>>(out, cnts);
}

// Round 2
// 254.656 us; speedup vs baseline: 1.7790x; 1.7790x over previous
//
#include <hip/hip_runtime.h>

// Problem constants (from reference setup_inputs)
#define BB 8
#define CC 3
#define HH 512
#define WW 1024
#define HW (HH * WW)            // 524288 = 2^19
#define NTOT (BB * HW)          // 4194304
#define SAME_RANGE 0.2f

// Gather-window radius: sources with |target - source| <= R in both coords
// are handled by the tiled gather; the (expected ~57 of 4.2M for N(0,1) flow)
// rest go through the exact outlier fallback (dlut atomicMin + list).
#define R 4
#define TX 32
#define TY 32
#define RX (TX + 2 * R)         // 40
#define RY (TY + 2 * R)         // 40
#define REG (RX * RY)           // 1600
#define WIN (2 * R + 1)         // 9
#define CAP 16384               // outlier list capacity (expected ~57 used)
#define DLUT_SENTINEL 0x7F7F7F7F  // memset(0x7F) ~= 3.39e38f; depth in [0,1) always below

// Pass 1: detect outlier sources (displacement > R). For each: atomicMin its
// depth into dlut[target] (int bits monotone for non-negative floats) and
// append (target, depth, obj[3]) to the list. Everything else is a no-op.
__global__ void prep_kernel(const float* __restrict__ flow,
                            const float* __restrict__ depth,
                            const float* __restrict__ obj,
                            int* __restrict__ dlut,
                            int* __restrict__ counter,
                            float* __restrict__ list) {
    int tid = blockIdx.x * blockDim.x + threadIdx.x;
    int b = tid >> 19;
    int rem = tid & (HW - 1);
    int y = rem >> 10;
    int x = rem & (WW - 1);
    float fx = flow[(b * 2 + 0) * HW + rem] + (float)x;
    float fy = flow[(b * 2 + 1) * HW + rem] + (float)y;
    fx = fminf(fmaxf(fx, 0.0f), (float)(WW - 1));
    fy = fminf(fmaxf(fy, 0.0f), (float)(HH - 1));
    int xi = (int)rintf(fx);    // round-half-to-even == jnp.round
    int yi = (int)rintf(fy);
    int dx = xi - x; if (dx < 0) dx = -dx;
    int dy = yi - y; if (dy < 0) dy = -dy;
    if (dx > R || dy > R) {
        int idx = b * HW + yi * WW + xi;
        float d = depth[tid];
        atomicMin(&dlut[idx], __float_as_int(d));
        int pos = atomicAdd(counter, 1);
        if (pos < CAP) {
            float* e = list + (size_t)pos * 8;
            e[0] = __int_as_float(idx);
            e[1] = d;
            e[2] = obj[(b * CC + 0) * HW + rem];
            e[3] = obj[(b * CC + 1) * HW + rem];
            e[4] = obj[(b * CC + 2) * HW + rem];
        }
    }
}

// Pass 2: tiled gather. Block = 32x32 target tile; stage the 40x40 source
// halo (target-idx+depth interleaved, obj channels) in LDS; each target scans
// its 9x9 source window: pass A computes depth-min + match bitmask, pass B
// accumulates keepers from the mask. Outlier-flagged targets (dlut != sentinel)
// additionally fold in matching list entries. Plain coalesced stores; no atomics.
__global__ __launch_bounds__(256) void gather_kernel(
        const float* __restrict__ obj,
        const float* __restrict__ flow,
        const float* __restrict__ depth,
        const int* __restrict__ dlut,
        const int* __restrict__ counter,
        const float* __restrict__ list,
        float* __restrict__ out) {
    __shared__ int2  s_id[REG];              // (target idx, depth bits)
    __shared__ float s_o0[REG], s_o1[REG], s_o2[REG];

    int b = blockIdx.z;
    int tx0 = blockIdx.x * TX;
    int ty0 = blockIdx.y * TY;
    int tid = threadIdx.x;

    // Stage source halo region into LDS (1600 entries / 256 threads = 6.25).
    for (int i = tid; i < REG; i += 256) {
        int sy = i / RX;
        int sx = i - sy * RX;
        int gy = ty0 - R + sy;
        int gx = tx0 - R + sx;
        int idxv = -1;
        float dv = 0.0f, o0 = 0.0f, o1 = 0.0f, o2 = 0.0f;
        if (gx >= 0 && gx < WW && gy >= 0 && gy < HH) {
            int rem = gy * WW + gx;
            float fx = flow[(b * 2 + 0) * HW + rem] + (float)gx;
            float fy = flow[(b * 2 + 1) * HW + rem] + (float)gy;
            fx = fminf(fmaxf(fx, 0.0f), (float)(WW - 1));
            fy = fminf(fmaxf(fy, 0.0f), (float)(HH - 1));
            int xi = (int)rintf(fx);
            int yi = (int)rintf(fy);
            idxv = b * HW + yi * WW + xi;
            dv = depth[b * HW + rem];
            o0 = obj[(b * CC + 0) * HW + rem];
            o1 = obj[(b * CC + 1) * HW + rem];
            o2 = obj[(b * CC + 2) * HW + rem];
        }
        s_id[i] = make_int2(idxv, __float_as_int(dv));
        s_o0[i] = o0; s_o1[i] = o1; s_o2[i] = o2;
    }
    __syncthreads();

    const int noutl = *counter;   // uniform across grid (written by prep)

    int txl = tid & 31;           // target x within tile: lanes consecutive
    int tyl0 = tid >> 5;          // 0..7; each thread does rows +0,+8,+16,+24
    for (int rep = 0; rep < 4; ++rep) {
        int tyl = tyl0 + rep * 8;
        int tgx = tx0 + txl;
        int tgy = ty0 + tyl;
        int t = b * HW + tgy * WW + tgx;

        // Pass A: window scan for depth-min and match mask (81 bits).
        float dmin = 3.0e38f;
        unsigned long long m0 = 0ull;
        unsigned int m1 = 0u;
        int k = 0;
        for (int dy = 0; dy < WIN; ++dy) {
            int rowbase = (tyl + dy) * RX + txl;
            #pragma unroll
            for (int dx = 0; dx < WIN; ++dx, ++k) {
                int2 v = s_id[rowbase + dx];
                bool match = (v.x == t);
                if (match) {
                    dmin = fminf(dmin, __int_as_float(v.y));
                    if (k < 64) m0 |= (1ull << k);
                    else        m1 |= (1u << (k - 64));
                }
            }
        }

        int dl = DLUT_SENTINEL;
        if (noutl > 0) {
            dl = dlut[t];
            if (dl != DLUT_SENTINEL) dmin = fminf(dmin, __int_as_float(dl));
        }
        float thresh = dmin + SAME_RANGE;

        // Pass B: accumulate keepers from the mask (avg ~1 set bit).
        float s0 = 0.0f, s1 = 0.0f, s2 = 0.0f, cnt = 0.0f;
        while (m0) {
            int kk = __ffsll((unsigned long long)m0) - 1;
            m0 &= m0 - 1;
            int dy = kk / WIN, dx = kk - dy * WIN;
            int a = (tyl + dy) * RX + txl + dx;
            if (__int_as_float(s_id[a].y) <= thresh) {
                s0 += s_o0[a]; s1 += s_o1[a]; s2 += s_o2[a]; cnt += 1.0f;
            }
        }
        while (m1) {
            int kk = __ffs(m1) - 1;
            m1 &= m1 - 1;
            kk += 64;
            int dy = kk / WIN, dx = kk - dy * WIN;
            int a = (tyl + dy) * RX + txl + dx;
            if (__int_as_float(s_id[a].y) <= thresh) {
                s0 += s_o0[a]; s1 += s_o1[a]; s2 += s_o2[a]; cnt += 1.0f;
            }
        }

        // Outlier fold-in: only for flagged targets (~57 of 4.2M).
        if (dl != DLUT_SENTINEL) {
            int n = noutl < CAP ? noutl : CAP;
            for (int j = 0; j < n; ++j) {
                const float* e = list + (size_t)j * 8;
                if (__float_as_int(e[0]) == t) {
                    float d = e[1];
                    if (d <= thresh) {
                        s0 += e[2]; s1 += e[3]; s2 += e[4]; cnt += 1.0f;
                    }
                }
            }
        }

        int orem = tgy * WW + tgx;
        float r0 = 0.0f, r1 = 0.0f, r2 = 0.0f;
        if (cnt > 0.0f) {
            r0 = s0 / cnt; r1 = s1 / cnt; r2 = s2 / cnt;
        }
        out[(b * CC + 0) * HW + orem] = r0;
        out[(b * CC + 1) * HW + orem] = r1;
        out[(b * CC + 2) * HW + orem] = r2;
    }
}

extern "C" void kernel_launch(void* const* d_in, const int* in_sizes, int n_in,
                              void* d_out, int out_size, void* d_ws, size_t ws_size,
                              hipStream_t stream) {
    const float* obj   = (const float*)d_in[0];
    const float* flow  = (const float*)d_in[1];
    const float* depth = (const float*)d_in[2];
    float* out = (float*)d_out;

    int*   dlut    = (int*)d_ws;
    int*   counter = (int*)((char*)d_ws + (size_t)NTOT * sizeof(int));
    float* list    = (float*)((char*)d_ws + (size_t)NTOT * sizeof(int) + 256);

    hipMemsetAsync(dlut, 0x7F, (size_t)NTOT * sizeof(int), stream);   // sentinel
    hipMemsetAsync(counter, 0, sizeof(int), stream);

    prep_kernel<<<dim3(NTOT / 256), dim3(256), 0, stream>>>(
        flow, depth, obj, dlut, counter, list);

    gather_kernel<<<dim3(WW / TX, HH / TY, BB), dim3(256), 0, stream>>>(
        obj, flow, depth, dlut, counter, list, out);
}

// Round 4
// 205.090 us; speedup vs baseline: 2.2090x; 1.2417x over previous
//
#include <hip/hip_runtime.h>

// Problem constants (from reference setup_inputs)
#define BB 8
#define CC 3
#define HH 512
#define WW 1024
#define HW (HH * WW)            // 524288 = 2^19
#define NTOT (BB * HW)          // 4194304
#define SAME_RANGE 0.2f

// Partition of (source -> target) pairs:
//   displacement <= R in both coords  -> handled by the tile owning the TARGET
//                                        via the 40x40 source halo
//   displacement  > R in either coord -> exact outlier list (expected ~57 of
//                                        4.2M for N(0,1) flow)
#define R 4
#define TX 32
#define TY 32
#define TT (TX * TY)            // 1024 targets per block
#define RX (TX + 2 * R)         // 40
#define RY (TY + 2 * R)         // 40
#define REG (RX * RY)           // 1600 halo sources per block
#define E_PER 7                 // ceil(1600 / 256)
#define CAP 16384               // outlier list capacity (expected ~57 used)
#define D_SENTINEL 0x7F7F7F7F   // > any depth bit-pattern (depth in [0,1))

// Pass 1: outlier sources (|displacement| > R in either coord) appended to a
// global list as (target idx, depth, obj[3]).
__global__ void prep_kernel(const float* __restrict__ flow,
                            const float* __restrict__ depth,
                            const float* __restrict__ obj,
                            int* __restrict__ counter,
                            float* __restrict__ list) {
    int tid = blockIdx.x * blockDim.x + threadIdx.x;
    int b = tid >> 19;
    int rem = tid & (HW - 1);
    int y = rem >> 10;
    int x = rem & (WW - 1);
    float fx = flow[(b * 2 + 0) * HW + rem] + (float)x;
    float fy = flow[(b * 2 + 1) * HW + rem] + (float)y;
    fx = fminf(fmaxf(fx, 0.0f), (float)(WW - 1));
    fy = fminf(fmaxf(fy, 0.0f), (float)(HH - 1));
    int xi = (int)rintf(fx);    // round-half-to-even == jnp.round
    int yi = (int)rintf(fy);
    int dx = xi - x; if (dx < 0) dx = -dx;
    int dy = yi - y; if (dy < 0) dy = -dy;
    if (dx > R || dy > R) {
        int idx = b * HW + yi * WW + xi;
        float d = depth[tid];
        int pos = atomicAdd(counter, 1);
        if (pos < CAP) {
            float* e = list + (size_t)pos * 8;
            e[0] = __int_as_float(idx);
            e[1] = d;
            e[2] = obj[(b * CC + 0) * HW + rem];
            e[3] = obj[(b * CC + 1) * HW + rem];
            e[4] = obj[(b * CC + 2) * HW + rem];
        }
    }
}

// Pass 2: LDS-scatter gather. Block owns a 32x32 target tile. Halo sources
// with displacement <= R whose target lands in-tile: phase 1 LDS atomicMin
// z-buffer; phase 2 keep-test + LDS atomicAdd obj/count; phase 3 divide +
// coalesced store. Outlier list folded into both phases. No global atomics.
__global__ __launch_bounds__(256) void gather_kernel(
        const float* __restrict__ obj,
        const float* __restrict__ flow,
        const float* __restrict__ depth,
        const int* __restrict__ counter,
        const float* __restrict__ list,
        float* __restrict__ out) {
    __shared__ int   s_dmin[TT];
    __shared__ float s_s0[TT], s_s1[TT], s_s2[TT], s_cnt[TT];

    int b = blockIdx.z;
    int tx0 = blockIdx.x * TX;
    int ty0 = blockIdx.y * TY;
    int tid = threadIdx.x;

    for (int i = tid; i < TT; i += 256) {
        s_dmin[i] = D_SENTINEL;
        s_s0[i] = 0.0f; s_s1[i] = 0.0f; s_s2[i] = 0.0f; s_cnt[i] = 0.0f;
    }
    __syncthreads();

    // Phase 1: halo sources -> LDS z-buffer min. Cache (tloc, d, rem) in regs.
    int   e_tloc[E_PER];
    float e_d[E_PER];
    int   e_rem[E_PER];
    #pragma unroll
    for (int e = 0; e < E_PER; ++e) {
        int i = tid + e * 256;
        int tloc = -1; float dv = 0.0f; int remv = 0;
        if (i < REG) {
            int sy = i / RX;
            int sx = i - sy * RX;
            int gy = ty0 - R + sy;
            int gx = tx0 - R + sx;
            if (gx >= 0 && gx < WW && gy >= 0 && gy < HH) {
                int rem = gy * WW + gx;
                float fx = flow[(b * 2 + 0) * HW + rem] + (float)gx;
                float fy = flow[(b * 2 + 1) * HW + rem] + (float)gy;
                fx = fminf(fmaxf(fx, 0.0f), (float)(WW - 1));
                fy = fminf(fmaxf(fy, 0.0f), (float)(HH - 1));
                int xi = (int)rintf(fx);
                int yi = (int)rintf(fy);
                int ddx = xi - gx; if (ddx < 0) ddx = -ddx;
                int ddy = yi - gy; if (ddy < 0) ddy = -ddy;
                // displacement <= R only: outliers are handled EXCLUSIVELY by
                // the list (otherwise in-tile outliers double count).
                if (ddx <= R && ddy <= R) {
                    int lx = xi - tx0;
                    int ly = yi - ty0;
                    if (lx >= 0 && lx < TX && ly >= 0 && ly < TY) {
                        tloc = ly * TX + lx;
                        dv = depth[b * HW + rem];
                        remv = rem;
                        atomicMin(&s_dmin[tloc], __float_as_int(dv));
                    }
                }
            }
        }
        e_tloc[e] = tloc; e_d[e] = dv; e_rem[e] = remv;
    }

    // Outlier phase 1: fold list depths into the LDS z-buffer.
    int noutl = *counter;
    if (noutl > CAP) noutl = CAP;
    for (int j = tid; j < noutl; j += 256) {
        const float* e = list + (size_t)j * 8;
        int idx = __float_as_int(e[0]);
        if ((idx >> 19) == b) {
            int remt = idx & (HW - 1);
            int lx = (remt & (WW - 1)) - tx0;
            int ly = (remt >> 10) - ty0;
            if (lx >= 0 && lx < TX && ly >= 0 && ly < TY)
                atomicMin(&s_dmin[ly * TX + lx], __float_as_int(e[1]));
        }
    }
    __syncthreads();

    // Phase 2: keep-test + accumulate (obj read only by the owning block).
    #pragma unroll
    for (int e = 0; e < E_PER; ++e) {
        int tloc = e_tloc[e];
        if (tloc >= 0) {
            float thresh = __int_as_float(s_dmin[tloc]) + SAME_RANGE;
            if (e_d[e] <= thresh) {
                int rem = e_rem[e];
                atomicAdd(&s_s0[tloc], obj[(b * CC + 0) * HW + rem]);
                atomicAdd(&s_s1[tloc], obj[(b * CC + 1) * HW + rem]);
                atomicAdd(&s_s2[tloc], obj[(b * CC + 2) * HW + rem]);
                atomicAdd(&s_cnt[tloc], 1.0f);
            }
        }
    }
    // Outlier phase 2.
    for (int j = tid; j < noutl; j += 256) {
        const float* e = list + (size_t)j * 8;
        int idx = __float_as_int(e[0]);
        if ((idx >> 19) == b) {
            int remt = idx & (HW - 1);
            int lx = (remt & (WW - 1)) - tx0;
            int ly = (remt >> 10) - ty0;
            if (lx >= 0 && lx < TX && ly >= 0 && ly < TY) {
                int tloc = ly * TX + lx;
                float thresh = __int_as_float(s_dmin[tloc]) + SAME_RANGE;
                if (e[1] <= thresh) {
                    atomicAdd(&s_s0[tloc], e[2]);
                    atomicAdd(&s_s1[tloc], e[3]);
                    atomicAdd(&s_s2[tloc], e[4]);
                    atomicAdd(&s_cnt[tloc], 1.0f);
                }
            }
        }
    }
    __syncthreads();

    // Phase 3: divide + coalesced store.
    for (int i = tid; i < TT; i += 256) {
        int lx = i & (TX - 1);
        int ly = i >> 5;            // TX == 32
        int orem = (ty0 + ly) * WW + (tx0 + lx);
        float c = s_cnt[i];
        float r0 = 0.0f, r1 = 0.0f, r2 = 0.0f;
        if (c > 0.0f) {
            r0 = s_s0[i] / c; r1 = s_s1[i] / c; r2 = s_s2[i] / c;
        }
        out[(b * CC + 0) * HW + orem] = r0;
        out[(b * CC + 1) * HW + orem] = r1;
        out[(b * CC + 2) * HW + orem] = r2;
    }
}

extern "C" void kernel_launch(void* const* d_in, const int* in_sizes, int n_in,
                              void* d_out, int out_size, void* d_ws, size_t ws_size,
                              hipStream_t stream) {
    const float* obj   = (const float*)d_in[0];
    const float* flow  = (const float*)d_in[1];
    const float* depth = (const float*)d_in[2];
    float* out = (float*)d_out;

    int*   counter = (int*)d_ws;
    float* list    = (float*)((char*)d_ws + 256);

    hipMemsetAsync(counter, 0, sizeof(int), stream);

    prep_kernel<<<dim3(NTOT / 256), dim3(256), 0, stream>>>(
        flow, depth, obj, counter, list);

    gather_kernel<<<dim3(WW / TX, HH / TY, BB), dim3(256), 0, stream>>>(
        obj, flow, depth, counter, list, out);
}